// Round 5
// baseline (1938.714 us; speedup 1.0000x reference)
//
#include <hip/hip_runtime.h>

#define EMB 100
#define EMB2 50          // bf16 pairs per row (valid)
#define XSTRIDE 52       // padded row stride in dwords (16B-aligned rows)
#define NBUCK 512        // partition buckets: (col>>13)<<4 | (row>>14)
#define CHUNK 8192       // edges per workgroup in bucket passes

typedef __attribute__((ext_vector_type(8))) short short8;
typedef __attribute__((ext_vector_type(4))) float f32x4;

__device__ __forceinline__ int bucket_key(int row, int col) {
    return ((col >> 13) << 4) | (row >> 14);   // col-block MAJOR, row-bucket minor
}

// ---- bf16 helpers (packed in uint: low ushort = even elem) ----
__device__ __forceinline__ float bflo(unsigned u) { return __uint_as_float(u << 16); }
__device__ __forceinline__ float bfhi(unsigned u) { return __uint_as_float(u & 0xFFFF0000u); }
__device__ __forceinline__ unsigned packbf(float a, float b) {
    unsigned ua = __float_as_uint(a), ub = __float_as_uint(b);
    unsigned ra = (ua + 0x7FFFu + ((ua >> 16) & 1u)) >> 16;   // RNE
    unsigned rb = (ub + 0x7FFFu + ((ub >> 16) & 1u)) >> 16;
    return ra | (rb << 16);
}
__device__ __forceinline__ unsigned short bf16rne(float f) {
    unsigned u = __float_as_uint(f);
    return (unsigned short)((u + 0x7FFFu + ((u >> 16) & 1u)) >> 16);
}

// ---------------- bucket count (LDS-aggregated) ----------------
__global__ __launch_bounds__(256) void k_bucket_count(const int* __restrict__ rows,
                                                      const int* __restrict__ cols,
                                                      int* __restrict__ gcnt, int E) {
    __shared__ int hist[NBUCK];
    int tid = threadIdx.x;
    int base = blockIdx.x * CHUNK;
    for (int s = tid; s < NBUCK; s += 256) hist[s] = 0;
    __syncthreads();
#pragma unroll
    for (int k = 0; k < CHUNK / 256; ++k) {
        int i = base + tid + k * 256;
        if (i < E) atomicAdd(&hist[bucket_key(rows[i], cols[i])], 1);
    }
    __syncthreads();
    for (int s = tid; s < NBUCK; s += 256)
        if (hist[s]) atomicAdd(&gcnt[s], hist[s]);
}

// ---------------- partition into (col-block, row-bucket) groups --------------
// part[pos] = {row, col | (q14 << 18)}  with q14 = round(val * 16383)
__global__ __launch_bounds__(256) void k_partition(const int* __restrict__ rows,
                                                   const int* __restrict__ cols,
                                                   const float* __restrict__ vals,
                                                   int* __restrict__ bucket_next,
                                                   int2* __restrict__ part, int E) {
    __shared__ int hist[NBUCK];
    __shared__ int base_s[NBUCK];
    __shared__ int cnt2[NBUCK];
    int tid = threadIdx.x;
    int base = blockIdx.x * CHUNK;
    for (int s = tid; s < NBUCK; s += 256) hist[s] = 0;
    __syncthreads();
#pragma unroll
    for (int k = 0; k < CHUNK / 256; ++k) {
        int i = base + tid + k * 256;
        if (i < E) atomicAdd(&hist[bucket_key(rows[i], cols[i])], 1);
    }
    __syncthreads();
    for (int s = tid; s < NBUCK; s += 256) {
        if (hist[s]) base_s[s] = atomicAdd(&bucket_next[s], hist[s]);
        cnt2[s] = 0;
    }
    __syncthreads();
#pragma unroll
    for (int k = 0; k < CHUNK / 256; ++k) {
        int i = base + tid + k * 256;
        if (i < E) {
            int r = rows[i], c = cols[i];
            int b = bucket_key(r, c);
            unsigned q = (unsigned)__float2int_rn(vals[i] * 16383.f);
            unsigned cv = (unsigned)c | (q << 18);
            int rank = atomicAdd(&cnt2[b], 1);
            part[base_s[b] + rank] = make_int2(r, (int)cv);
        }
    }
}

// ---------------- row histogram over partitioned edges (L2-local) ------------
__global__ __launch_bounds__(256) void k_hist2(const int2* __restrict__ part,
                                               int* __restrict__ cnt, int E) {
    int i = blockIdx.x * 256 + threadIdx.x;
    if (i < E) atomicAdd(&cnt[part[i].x], 1);
}

// ---------------- final CSR scatter (L2-local, ~col-ordered per row) ---------
__global__ __launch_bounds__(256) void k_scatter2(const int2* __restrict__ part,
                                                  int* __restrict__ nextp,
                                                  unsigned* __restrict__ csr, int E) {
    int i = blockIdx.x * 256 + threadIdx.x;
    if (i < E) {
        int2 e = part[i];
        int pos = atomicAdd(&nextp[e.x], 1);
        csr[pos] = (unsigned)e.y;
    }
}

// ---------------- scans ----------------
__global__ __launch_bounds__(256) void k_scan1(const int* __restrict__ cnt,
                                               int* __restrict__ outp,
                                               int* __restrict__ bsum, int n) {
    __shared__ int tmp[256];
    int i = blockIdx.x * 256 + threadIdx.x;
    int v = (i < n) ? cnt[i] : 0;
    tmp[threadIdx.x] = v;
    __syncthreads();
    for (int off = 1; off < 256; off <<= 1) {
        int t = (threadIdx.x >= off) ? tmp[threadIdx.x - off] : 0;
        __syncthreads();
        tmp[threadIdx.x] += t;
        __syncthreads();
    }
    if (i < n) outp[i] = tmp[threadIdx.x] - v;   // exclusive
    if (threadIdx.x == 255) bsum[blockIdx.x] = tmp[255];
}

__global__ __launch_bounds__(1024) void k_scan2(int* __restrict__ bsum, int nb) {
    __shared__ int tmp[1024];
    int v = (threadIdx.x < nb) ? bsum[threadIdx.x] : 0;
    tmp[threadIdx.x] = v;
    __syncthreads();
    for (int off = 1; off < 1024; off <<= 1) {
        int t = (threadIdx.x >= off) ? tmp[threadIdx.x - off] : 0;
        __syncthreads();
        tmp[threadIdx.x] += t;
        __syncthreads();
    }
    if (threadIdx.x < nb) bsum[threadIdx.x] = tmp[threadIdx.x] - v; // exclusive
}

__global__ __launch_bounds__(256) void k_scan3(int* __restrict__ outp,
                                               const int* __restrict__ bsum,
                                               int n, int E) {
    int i = blockIdx.x * 256 + threadIdx.x;
    if (i < n) outp[i] += bsum[blockIdx.x];
    if (i == 0) outp[n] = E;
}

__global__ __launch_bounds__(256) void k_copy(int* __restrict__ dst,
                                              const int* __restrict__ src, int n) {
    int i = blockIdx.x * 256 + threadIdx.x;
    if (i < n) dst[i] = src[i];
}

// ---------------- MFMA GEMM: Y[r][e] = sum_d X[r][d] * W[e][d] ----------------
// A[m][k] = X[rowbase+m][k]  (m = lane&15, k = (lane>>4)*8 + j)
// B[k][n] = W[nt*16+n][k]    (n = lane&15, same k), staged bf16 in LDS
// C/D: col = lane&15, row = (lane>>4)*4 + reg   [verified layout]
template <bool F32SRC>
__global__ __launch_bounds__(256) void k_gemm_mfma(const void* __restrict__ Xv,
                                                   const float* __restrict__ W,
                                                   unsigned* __restrict__ Y,
                                                   int nTiles, int N) {
    __shared__ uint4 Bf[28][64];   // [nt*4+ks][lane]
    int tid = threadIdx.x;
#pragma unroll
    for (int it = 0; it < 7; ++it) {
        int id = it * 256 + tid;
        int fs = id >> 6, lane = id & 63;
        int nt = fs >> 2, ks = fs & 3;
        int e = nt * 16 + (lane & 15);
        int dbase = ks * 32 + (lane >> 4) * 8;
        float w[8];
#pragma unroll
        for (int j = 0; j < 8; ++j) {
            int d = dbase + j;
            w[j] = (e < EMB && d < EMB) ? W[e * EMB + d] : 0.f;
        }
        uint4 u;
        u.x = packbf(w[0], w[1]); u.y = packbf(w[2], w[3]);
        u.z = packbf(w[4], w[5]); u.w = packbf(w[6], w[7]);
        Bf[fs][lane] = u;
    }
    __syncthreads();

    int wid = (blockIdx.x * 256 + tid) >> 6;
    int nWaves = gridDim.x * 4;
    int lane = tid & 63;
    int m = lane & 15, kg = lane >> 4;

    for (int tile = wid; tile < nTiles; tile += nWaves) {
        int rowbase = tile * 16;
        int arow = rowbase + m; if (arow >= N) arow = N - 1;   // clamp (masked at store)
        uint4 a[4];
        if (F32SRC) {
            const float* xr = (const float*)Xv + (size_t)arow * EMB;
#pragma unroll
            for (int ks = 0; ks < 3; ++ks) {
                float4 v0 = *(const float4*)(xr + ks * 32 + kg * 8);
                float4 v1 = *(const float4*)(xr + ks * 32 + kg * 8 + 4);
                a[ks] = make_uint4(packbf(v0.x, v0.y), packbf(v0.z, v0.w),
                                   packbf(v1.x, v1.y), packbf(v1.z, v1.w));
            }
            uint4 t = make_uint4(0, 0, 0, 0);
            if (kg == 0) { float4 v = *(const float4*)(xr + 96);
                           t.x = packbf(v.x, v.y); t.y = packbf(v.z, v.w); }
            a[3] = t;
        } else {
            const unsigned* xr = (const unsigned*)Xv + (size_t)arow * XSTRIDE;
#pragma unroll
            for (int ks = 0; ks < 3; ++ks)
                a[ks] = *(const uint4*)(xr + ks * 16 + kg * 4);
            uint4 t = make_uint4(0, 0, 0, 0);
            if (kg == 0) { uint2 v = *(const uint2*)(xr + 48); t.x = v.x; t.y = v.y; }
            a[3] = t;
        }

        f32x4 acc[7];
#pragma unroll
        for (int nt = 0; nt < 7; ++nt) acc[nt] = (f32x4){0.f, 0.f, 0.f, 0.f};
#pragma unroll
        for (int ks = 0; ks < 4; ++ks) {
            short8 av = __builtin_bit_cast(short8, a[ks]);
#pragma unroll
            for (int nt = 0; nt < 7; ++nt) {
                short8 bv = __builtin_bit_cast(short8, Bf[nt * 4 + ks][lane]);
                acc[nt] = __builtin_amdgcn_mfma_f32_16x16x32_bf16(av, bv, acc[nt], 0, 0, 0);
            }
        }
        unsigned short* Yu = (unsigned short*)Y;
#pragma unroll
        for (int nt = 0; nt < 7; ++nt) {
            int e = nt * 16 + m;
            if (e < EMB) {
#pragma unroll
                for (int r = 0; r < 4; ++r) {
                    int rr = rowbase + kg * 4 + r;
                    if (rr < N)
                        Yu[(size_t)rr * (XSTRIDE * 2) + e] = bf16rne(acc[nt][r]);
                }
            }
        }
    }
}

// ---------------- SpMM + norm + mean-accumulate ----------------
// One wave per row; lanes 0..49 own a bf16 pair. csr word = col | (q14<<18).
// Edges are ~col-block-sorted within each row -> gathers walk a sliding
// L2-resident window. Out[row] = prev[row]*pscale + normalized(acc)*scale
__global__ __launch_bounds__(256) void k_spmm_norm(const int* __restrict__ row_ptr,
                                                   const unsigned* __restrict__ csr,
                                                   const unsigned* __restrict__ Y,
                                                   unsigned* __restrict__ Xout,
                                                   float* __restrict__ Out,
                                                   const float* __restrict__ prev,
                                                   float pscale, float scale,
                                                   int writeX, int N) {
    int wave = (blockIdx.x * 256 + threadIdx.x) >> 6;
    int lane = threadIdx.x & 63;
    if (wave >= N) return;
    int beg = row_ptr[wave], end = row_ptr[wave + 1];
    const float dq = 1.0f / 16383.f;
    float a0 = 0.f, a1 = 0.f;
    if (lane < EMB2) {
        const unsigned* yb = Y + lane;
        int j = beg;
        for (; j + 7 < end; j += 8) {
            unsigned u0 = __builtin_nontemporal_load(&csr[j + 0]);
            unsigned u1 = __builtin_nontemporal_load(&csr[j + 1]);
            unsigned u2 = __builtin_nontemporal_load(&csr[j + 2]);
            unsigned u3 = __builtin_nontemporal_load(&csr[j + 3]);
            unsigned u4 = __builtin_nontemporal_load(&csr[j + 4]);
            unsigned u5 = __builtin_nontemporal_load(&csr[j + 5]);
            unsigned u6 = __builtin_nontemporal_load(&csr[j + 6]);
            unsigned u7 = __builtin_nontemporal_load(&csr[j + 7]);
            unsigned y0 = yb[(size_t)(u0 & 0x3FFFFu) * XSTRIDE];
            unsigned y1 = yb[(size_t)(u1 & 0x3FFFFu) * XSTRIDE];
            unsigned y2 = yb[(size_t)(u2 & 0x3FFFFu) * XSTRIDE];
            unsigned y3 = yb[(size_t)(u3 & 0x3FFFFu) * XSTRIDE];
            unsigned y4 = yb[(size_t)(u4 & 0x3FFFFu) * XSTRIDE];
            unsigned y5 = yb[(size_t)(u5 & 0x3FFFFu) * XSTRIDE];
            unsigned y6 = yb[(size_t)(u6 & 0x3FFFFu) * XSTRIDE];
            unsigned y7 = yb[(size_t)(u7 & 0x3FFFFu) * XSTRIDE];
            float v0 = (float)(u0 >> 18) * dq, v1 = (float)(u1 >> 18) * dq;
            float v2 = (float)(u2 >> 18) * dq, v3 = (float)(u3 >> 18) * dq;
            float v4 = (float)(u4 >> 18) * dq, v5 = (float)(u5 >> 18) * dq;
            float v6 = (float)(u6 >> 18) * dq, v7 = (float)(u7 >> 18) * dq;
            a0 = fmaf(v0, bflo(y0), a0); a1 = fmaf(v0, bfhi(y0), a1);
            a0 = fmaf(v1, bflo(y1), a0); a1 = fmaf(v1, bfhi(y1), a1);
            a0 = fmaf(v2, bflo(y2), a0); a1 = fmaf(v2, bfhi(y2), a1);
            a0 = fmaf(v3, bflo(y3), a0); a1 = fmaf(v3, bfhi(y3), a1);
            a0 = fmaf(v4, bflo(y4), a0); a1 = fmaf(v4, bfhi(y4), a1);
            a0 = fmaf(v5, bflo(y5), a0); a1 = fmaf(v5, bfhi(y5), a1);
            a0 = fmaf(v6, bflo(y6), a0); a1 = fmaf(v6, bfhi(y6), a1);
            a0 = fmaf(v7, bflo(y7), a0); a1 = fmaf(v7, bfhi(y7), a1);
        }
        for (; j < end; ++j) {
            unsigned u = csr[j];
            unsigned y = yb[(size_t)(u & 0x3FFFFu) * XSTRIDE];
            float v = (float)(u >> 18) * dq;
            a0 = fmaf(v, bflo(y), a0); a1 = fmaf(v, bfhi(y), a1);
        }
    }
    float ss = fmaf(a0, a0, a1 * a1);
#pragma unroll
    for (int off = 32; off; off >>= 1) ss += __shfl_xor(ss, off, 64);
    float sc = scale / fmaxf(sqrtf(ss), 1e-12f);
    if (lane < EMB2) {
        if (writeX) Xout[(size_t)wave * XSTRIDE + lane] = packbf(a0, a1);
        float2 p = *((const float2*)(prev + (size_t)wave * EMB) + lane);
        float2 o;
        o.x = fmaf(a0, sc, p.x * pscale);
        o.y = fmaf(a1, sc, p.y * pscale);
        *((float2*)(Out + (size_t)wave * EMB) + lane) = o;
    }
}

extern "C" void kernel_launch(void* const* d_in, const int* in_sizes, int n_in,
                              void* d_out, int out_size, void* d_ws, size_t ws_size,
                              hipStream_t stream) {
    const float* emb   = (const float*)d_in[0];
    const float* avals = (const float*)d_in[1];
    const float* wts   = (const float*)d_in[2];
    const int*   arows = (const int*)d_in[3];
    const int*   acols = (const int*)d_in[4];

    const int N = in_sizes[0] / EMB;
    const int E = in_sizes[1];
    const int L = in_sizes[2] / (EMB * EMB);
    const float scale = 1.0f / (float)(L + 1);

    // workspace layout (dwords). `part` aliases bufY/bufX (only live pre-GEMM).
    unsigned* bufY   = (unsigned*)d_ws;                      // N*XSTRIDE
    unsigned* bufX   = bufY + (size_t)N * XSTRIDE;           // N*XSTRIDE
    int* row_ptr     = (int*)(bufX + (size_t)N * XSTRIDE);   // N+2
    int* nextp       = row_ptr + (N + 2);                    // N
    int* bsum        = nextp + N;                            // 1024
    int* bucket_next = bsum + 1024;                          // NBUCK
    unsigned* csr    = (unsigned*)(bucket_next + NBUCK);     // E
    int2* part       = (int2*)d_ws;                          // E int2 (aliased)
    float* out = (float*)d_out;

    const int nb_scan = (N + 255) / 256;
    const int nchunk = (E + CHUNK - 1) / CHUNK;

    // ---- CSR build: (col-block, row-bucket) partition, then L2-local passes --
    hipMemsetAsync(bucket_next, 0, NBUCK * sizeof(int), stream);
    hipMemsetAsync(nextp, 0, (size_t)N * sizeof(int), stream);
    k_bucket_count<<<nchunk, 256, 0, stream>>>(arows, acols, bucket_next, E);
    k_scan2<<<1, 1024, 0, stream>>>(bucket_next, NBUCK);
    k_partition<<<nchunk, 256, 0, stream>>>(arows, acols, avals, bucket_next,
                                            part, E);
    k_hist2<<<(E + 255) / 256, 256, 0, stream>>>(part, nextp, E);
    k_scan1<<<nb_scan, 256, 0, stream>>>(nextp, row_ptr, bsum, N);
    k_scan2<<<1, 1024, 0, stream>>>(bsum, nb_scan);
    k_scan3<<<nb_scan, 256, 0, stream>>>(row_ptr, bsum, N, E);
    k_copy<<<nb_scan, 256, 0, stream>>>(nextp, row_ptr, N);
    k_scatter2<<<(E + 255) / 256, 256, 0, stream>>>(part, nextp, csr, E);

    const int nTiles = (N + 15) / 16;
    const int gemm_blocks = 782;
    const int spmm_blocks = (N + 3) / 4;

    // layer 0: Out = emb*scale + norm0*scale
    k_gemm_mfma<true><<<gemm_blocks, 256, 0, stream>>>(emb, wts, bufY, nTiles, N);
    k_spmm_norm<<<spmm_blocks, 256, 0, stream>>>(row_ptr, csr, bufY, bufX,
                                                 out, emb, scale, scale, 1, N);
    // layers 1..L-1: Out += norm_l*scale
    for (int l = 1; l < L; ++l) {
        k_gemm_mfma<false><<<gemm_blocks, 256, 0, stream>>>(
            bufX, wts + (size_t)l * EMB * EMB, bufY, nTiles, N);
        k_spmm_norm<<<spmm_blocks, 256, 0, stream>>>(row_ptr, csr, bufY, bufX,
                                                     out, out, 1.0f, scale,
                                                     (l < L - 1) ? 1 : 0, N);
    }
}

// Round 6
// 1281.679 us; speedup vs baseline: 1.5126x; 1.5126x over previous
//
#include <hip/hip_runtime.h>

#define EMB 100
#define EMB2 50          // bf16 pairs per row (valid)
#define XSTRIDE 52       // padded row stride in dwords (16B-aligned rows)
#define BSHIFT 8         // bucket = row >> 8  (256 rows/bucket)
#define BROWS 256        // rows per bucket
#define MAXBUCK 1024
#define CHUNK 8192       // edges per workgroup in bucket passes

typedef __attribute__((ext_vector_type(8))) short short8;
typedef __attribute__((ext_vector_type(4))) float f32x4;

// ---- bf16 helpers (packed in uint: low ushort = even elem) ----
__device__ __forceinline__ float bflo(unsigned u) { return __uint_as_float(u << 16); }
__device__ __forceinline__ float bfhi(unsigned u) { return __uint_as_float(u & 0xFFFF0000u); }
__device__ __forceinline__ unsigned packbf(float a, float b) {
    unsigned ua = __float_as_uint(a), ub = __float_as_uint(b);
    unsigned ra = (ua + 0x7FFFu + ((ua >> 16) & 1u)) >> 16;   // RNE
    unsigned rb = (ub + 0x7FFFu + ((ub >> 16) & 1u)) >> 16;
    return ra | (rb << 16);
}
__device__ __forceinline__ unsigned short bf16rne(float f) {
    unsigned u = __float_as_uint(f);
    return (unsigned short)((u + 0x7FFFu + ((u >> 16) & 1u)) >> 16);
}

// ---------------- bucket count (LDS-aggregated) ----------------
__global__ __launch_bounds__(256) void k_bucket_count(const int* __restrict__ rows,
                                                      int* __restrict__ gcnt,
                                                      int E, int nbuck) {
    __shared__ int hist[MAXBUCK];
    int tid = threadIdx.x;
    int base = blockIdx.x * CHUNK;
    for (int s = tid; s < nbuck; s += 256) hist[s] = 0;
    __syncthreads();
#pragma unroll
    for (int k = 0; k < CHUNK / 256; ++k) {
        int i = base + tid + k * 256;
        if (i < E) atomicAdd(&hist[rows[i] >> BSHIFT], 1);
    }
    __syncthreads();
    for (int s = tid; s < nbuck; s += 256)
        if (hist[s]) atomicAdd(&gcnt[s], hist[s]);
}

// ---------------- exclusive scan over buckets (single block) ----------------
__global__ __launch_bounds__(1024) void k_scan2(int* __restrict__ bsum, int nb) {
    __shared__ int tmp[1024];
    int v = (threadIdx.x < nb) ? bsum[threadIdx.x] : 0;
    tmp[threadIdx.x] = v;
    __syncthreads();
    for (int off = 1; off < 1024; off <<= 1) {
        int t = (threadIdx.x >= off) ? tmp[threadIdx.x - off] : 0;
        __syncthreads();
        tmp[threadIdx.x] += t;
        __syncthreads();
    }
    if (threadIdx.x < nb) bsum[threadIdx.x] = tmp[threadIdx.x] - v; // exclusive
}

// ---------------- partition into row-buckets ----------------
// part[pos] = {row, col | (q14 << 18)}.  After this kernel, bucket_next[b]
// has been atomically advanced to the END offset of bucket b (inclusive scan).
__global__ __launch_bounds__(256) void k_partition(const int* __restrict__ rows,
                                                   const int* __restrict__ cols,
                                                   const float* __restrict__ vals,
                                                   int* __restrict__ bucket_next,
                                                   int2* __restrict__ part,
                                                   int E, int nbuck) {
    __shared__ int hist[MAXBUCK];
    __shared__ int base_s[MAXBUCK];
    __shared__ int cnt2[MAXBUCK];
    int tid = threadIdx.x;
    int base = blockIdx.x * CHUNK;
    for (int s = tid; s < nbuck; s += 256) hist[s] = 0;
    __syncthreads();
#pragma unroll
    for (int k = 0; k < CHUNK / 256; ++k) {
        int i = base + tid + k * 256;
        if (i < E) atomicAdd(&hist[rows[i] >> BSHIFT], 1);
    }
    __syncthreads();
    for (int s = tid; s < nbuck; s += 256) {
        if (hist[s]) base_s[s] = atomicAdd(&bucket_next[s], hist[s]);
        cnt2[s] = 0;
    }
    __syncthreads();
#pragma unroll
    for (int k = 0; k < CHUNK / 256; ++k) {
        int i = base + tid + k * 256;
        if (i < E) {
            int r = rows[i];
            int b = r >> BSHIFT;
            unsigned q = (unsigned)__float2int_rn(vals[i] * 16383.f);
            unsigned cv = (unsigned)cols[i] | (q << 18);
            int rank = atomicAdd(&cnt2[b], 1);
            part[base_s[b] + rank] = make_int2(r, (int)cv);
        }
    }
}

// ---------------- per-bucket CSR finalize ----------------
// One WG per bucket: LDS row-hist over the bucket's part segment, LDS scan
// -> row_ptr, LDS-cursor scatter into the bucket's contiguous csr window.
// Replaces hist2 + scan1/2/3 + copy + scatter2; all counters in LDS, csr
// writes confined to a 32 KB window per WG (no write amplification).
__global__ __launch_bounds__(256) void k_build_csr(const int2* __restrict__ part,
                                                   const int* __restrict__ bucket_end,
                                                   int* __restrict__ row_ptr,
                                                   unsigned* __restrict__ csr,
                                                   int N, int E) {
    __shared__ int cnt[BROWS];
    __shared__ int scn[BROWS];
    __shared__ int cur[BROWS];
    int b = blockIdx.x;
    int tid = threadIdx.x;
    int seg_beg = (b == 0) ? 0 : bucket_end[b - 1];
    int seg_end = bucket_end[b];
    int rowbase = b << BSHIFT;

    cnt[tid] = 0;
    __syncthreads();
    for (int i = seg_beg + tid; i < seg_end; i += 256)
        atomicAdd(&cnt[part[i].x - rowbase], 1);
    __syncthreads();
    int v = cnt[tid];
    scn[tid] = v;
    __syncthreads();
    for (int off = 1; off < 256; off <<= 1) {
        int t = (tid >= off) ? scn[tid - off] : 0;
        __syncthreads();
        scn[tid] += t;
        __syncthreads();
    }
    int rp = seg_beg + scn[tid] - v;          // exclusive
    if (rowbase + tid < N) row_ptr[rowbase + tid] = rp;
    cur[tid] = rp;
    if (b == 0 && tid == 0) row_ptr[N] = E;
    __syncthreads();
    for (int i = seg_beg + tid; i < seg_end; i += 256) {
        int2 e = part[i];
        int pos = atomicAdd(&cur[e.x - rowbase], 1);
        csr[pos] = (unsigned)e.y;
    }
}

// ---------------- MFMA GEMM: Y[r][e] = sum_d X[r][d] * W[e][d] ----------------
// A[m][k] = X[rowbase+m][k]  (m = lane&15, k = (lane>>4)*8 + j)
// B[k][n] = W[nt*16+n][k]    (n = lane&15, same k), staged bf16 in LDS
// C/D: col = lane&15, row = (lane>>4)*4 + reg   [verified layout]
template <bool F32SRC>
__global__ __launch_bounds__(256) void k_gemm_mfma(const void* __restrict__ Xv,
                                                   const float* __restrict__ W,
                                                   unsigned* __restrict__ Y,
                                                   int nTiles, int N) {
    __shared__ uint4 Bf[28][64];   // [nt*4+ks][lane]
    int tid = threadIdx.x;
#pragma unroll
    for (int it = 0; it < 7; ++it) {
        int id = it * 256 + tid;
        int fs = id >> 6, lane = id & 63;
        int nt = fs >> 2, ks = fs & 3;
        int e = nt * 16 + (lane & 15);
        int dbase = ks * 32 + (lane >> 4) * 8;
        float w[8];
#pragma unroll
        for (int j = 0; j < 8; ++j) {
            int d = dbase + j;
            w[j] = (e < EMB && d < EMB) ? W[e * EMB + d] : 0.f;
        }
        uint4 u;
        u.x = packbf(w[0], w[1]); u.y = packbf(w[2], w[3]);
        u.z = packbf(w[4], w[5]); u.w = packbf(w[6], w[7]);
        Bf[fs][lane] = u;
    }
    __syncthreads();

    int wid = (blockIdx.x * 256 + tid) >> 6;
    int nWaves = gridDim.x * 4;
    int lane = tid & 63;
    int m = lane & 15, kg = lane >> 4;

    for (int tile = wid; tile < nTiles; tile += nWaves) {
        int rowbase = tile * 16;
        int arow = rowbase + m; if (arow >= N) arow = N - 1;   // clamp (masked at store)
        uint4 a[4];
        if (F32SRC) {
            const float* xr = (const float*)Xv + (size_t)arow * EMB;
#pragma unroll
            for (int ks = 0; ks < 3; ++ks) {
                float4 v0 = *(const float4*)(xr + ks * 32 + kg * 8);
                float4 v1 = *(const float4*)(xr + ks * 32 + kg * 8 + 4);
                a[ks] = make_uint4(packbf(v0.x, v0.y), packbf(v0.z, v0.w),
                                   packbf(v1.x, v1.y), packbf(v1.z, v1.w));
            }
            uint4 t = make_uint4(0, 0, 0, 0);
            if (kg == 0) { float4 v = *(const float4*)(xr + 96);
                           t.x = packbf(v.x, v.y); t.y = packbf(v.z, v.w); }
            a[3] = t;
        } else {
            const unsigned* xr = (const unsigned*)Xv + (size_t)arow * XSTRIDE;
#pragma unroll
            for (int ks = 0; ks < 3; ++ks)
                a[ks] = *(const uint4*)(xr + ks * 16 + kg * 4);
            uint4 t = make_uint4(0, 0, 0, 0);
            if (kg == 0) { uint2 v = *(const uint2*)(xr + 48); t.x = v.x; t.y = v.y; }
            a[3] = t;
        }

        f32x4 acc[7];
#pragma unroll
        for (int nt = 0; nt < 7; ++nt) acc[nt] = (f32x4){0.f, 0.f, 0.f, 0.f};
#pragma unroll
        for (int ks = 0; ks < 4; ++ks) {
            short8 av = __builtin_bit_cast(short8, a[ks]);
#pragma unroll
            for (int nt = 0; nt < 7; ++nt) {
                short8 bv = __builtin_bit_cast(short8, Bf[nt * 4 + ks][lane]);
                acc[nt] = __builtin_amdgcn_mfma_f32_16x16x32_bf16(av, bv, acc[nt], 0, 0, 0);
            }
        }
        unsigned short* Yu = (unsigned short*)Y;
#pragma unroll
        for (int nt = 0; nt < 7; ++nt) {
            int e = nt * 16 + m;
            if (e < EMB) {
#pragma unroll
                for (int r = 0; r < 4; ++r) {
                    int rr = rowbase + kg * 4 + r;
                    if (rr < N)
                        Yu[(size_t)rr * (XSTRIDE * 2) + e] = bf16rne(acc[nt][r]);
                }
            }
        }
    }
}

// ---------------- SpMM + norm + mean-accumulate ----------------
// One wave per row; lanes 0..49 own a bf16 pair. csr word = col | (q14<<18).
// Out[row] = prev[row]*pscale + normalized(acc)*scale
__global__ __launch_bounds__(256) void k_spmm_norm(const int* __restrict__ row_ptr,
                                                   const unsigned* __restrict__ csr,
                                                   const unsigned* __restrict__ Y,
                                                   unsigned* __restrict__ Xout,
                                                   float* __restrict__ Out,
                                                   const float* __restrict__ prev,
                                                   float pscale, float scale,
                                                   int writeX, int N) {
    int wave = (blockIdx.x * 256 + threadIdx.x) >> 6;
    int lane = threadIdx.x & 63;
    if (wave >= N) return;
    int beg = row_ptr[wave], end = row_ptr[wave + 1];
    const float dq = 1.0f / 16383.f;
    float a0 = 0.f, a1 = 0.f;
    if (lane < EMB2) {
        const unsigned* yb = Y + lane;
        int j = beg;
        for (; j + 7 < end; j += 8) {
            unsigned u0 = __builtin_nontemporal_load(&csr[j + 0]);
            unsigned u1 = __builtin_nontemporal_load(&csr[j + 1]);
            unsigned u2 = __builtin_nontemporal_load(&csr[j + 2]);
            unsigned u3 = __builtin_nontemporal_load(&csr[j + 3]);
            unsigned u4 = __builtin_nontemporal_load(&csr[j + 4]);
            unsigned u5 = __builtin_nontemporal_load(&csr[j + 5]);
            unsigned u6 = __builtin_nontemporal_load(&csr[j + 6]);
            unsigned u7 = __builtin_nontemporal_load(&csr[j + 7]);
            unsigned y0 = yb[(size_t)(u0 & 0x3FFFFu) * XSTRIDE];
            unsigned y1 = yb[(size_t)(u1 & 0x3FFFFu) * XSTRIDE];
            unsigned y2 = yb[(size_t)(u2 & 0x3FFFFu) * XSTRIDE];
            unsigned y3 = yb[(size_t)(u3 & 0x3FFFFu) * XSTRIDE];
            unsigned y4 = yb[(size_t)(u4 & 0x3FFFFu) * XSTRIDE];
            unsigned y5 = yb[(size_t)(u5 & 0x3FFFFu) * XSTRIDE];
            unsigned y6 = yb[(size_t)(u6 & 0x3FFFFu) * XSTRIDE];
            unsigned y7 = yb[(size_t)(u7 & 0x3FFFFu) * XSTRIDE];
            float v0 = (float)(u0 >> 18) * dq, v1 = (float)(u1 >> 18) * dq;
            float v2 = (float)(u2 >> 18) * dq, v3 = (float)(u3 >> 18) * dq;
            float v4 = (float)(u4 >> 18) * dq, v5 = (float)(u5 >> 18) * dq;
            float v6 = (float)(u6 >> 18) * dq, v7 = (float)(u7 >> 18) * dq;
            a0 = fmaf(v0, bflo(y0), a0); a1 = fmaf(v0, bfhi(y0), a1);
            a0 = fmaf(v1, bflo(y1), a0); a1 = fmaf(v1, bfhi(y1), a1);
            a0 = fmaf(v2, bflo(y2), a0); a1 = fmaf(v2, bfhi(y2), a1);
            a0 = fmaf(v3, bflo(y3), a0); a1 = fmaf(v3, bfhi(y3), a1);
            a0 = fmaf(v4, bflo(y4), a0); a1 = fmaf(v4, bfhi(y4), a1);
            a0 = fmaf(v5, bflo(y5), a0); a1 = fmaf(v5, bfhi(y5), a1);
            a0 = fmaf(v6, bflo(y6), a0); a1 = fmaf(v6, bfhi(y6), a1);
            a0 = fmaf(v7, bflo(y7), a0); a1 = fmaf(v7, bfhi(y7), a1);
        }
        for (; j < end; ++j) {
            unsigned u = csr[j];
            unsigned y = yb[(size_t)(u & 0x3FFFFu) * XSTRIDE];
            float v = (float)(u >> 18) * dq;
            a0 = fmaf(v, bflo(y), a0); a1 = fmaf(v, bfhi(y), a1);
        }
    }
    float ss = fmaf(a0, a0, a1 * a1);
#pragma unroll
    for (int off = 32; off; off >>= 1) ss += __shfl_xor(ss, off, 64);
    float sc = scale / fmaxf(sqrtf(ss), 1e-12f);
    if (lane < EMB2) {
        if (writeX) Xout[(size_t)wave * XSTRIDE + lane] = packbf(a0, a1);
        float2 p = *((const float2*)(prev + (size_t)wave * EMB) + lane);
        float2 o;
        o.x = fmaf(a0, sc, p.x * pscale);
        o.y = fmaf(a1, sc, p.y * pscale);
        *((float2*)(Out + (size_t)wave * EMB) + lane) = o;
    }
}

extern "C" void kernel_launch(void* const* d_in, const int* in_sizes, int n_in,
                              void* d_out, int out_size, void* d_ws, size_t ws_size,
                              hipStream_t stream) {
    const float* emb   = (const float*)d_in[0];
    const float* avals = (const float*)d_in[1];
    const float* wts   = (const float*)d_in[2];
    const int*   arows = (const int*)d_in[3];
    const int*   acols = (const int*)d_in[4];

    const int N = in_sizes[0] / EMB;
    const int E = in_sizes[1];
    const int L = in_sizes[2] / (EMB * EMB);
    const float scale = 1.0f / (float)(L + 1);
    const int nbuck = (N + BROWS - 1) >> BSHIFT;

    // workspace layout (dwords). `part` aliases bufY/bufX (only live pre-GEMM).
    unsigned* bufY   = (unsigned*)d_ws;                      // N*XSTRIDE
    unsigned* bufX   = bufY + (size_t)N * XSTRIDE;           // N*XSTRIDE
    int* row_ptr     = (int*)(bufX + (size_t)N * XSTRIDE);   // N+2
    int* bucket_next = row_ptr + (N + 2);                    // MAXBUCK
    unsigned* csr    = (unsigned*)(bucket_next + MAXBUCK);   // E
    int2* part       = (int2*)d_ws;                          // E int2 (aliased)
    float* out = (float*)d_out;

    const int nchunk = (E + CHUNK - 1) / CHUNK;

    // ---- CSR build: row-bucket partition + fused per-bucket finalize ----
    hipMemsetAsync(bucket_next, 0, MAXBUCK * sizeof(int), stream);
    k_bucket_count<<<nchunk, 256, 0, stream>>>(arows, bucket_next, E, nbuck);
    k_scan2<<<1, 1024, 0, stream>>>(bucket_next, nbuck);
    k_partition<<<nchunk, 256, 0, stream>>>(arows, acols, avals, bucket_next,
                                            part, E, nbuck);
    k_build_csr<<<nbuck, 256, 0, stream>>>(part, bucket_next, row_ptr, csr, N, E);

    const int nTiles = (N + 15) / 16;
    const int gemm_blocks = 782;
    const int spmm_blocks = (N + 3) / 4;

    // layer 0: Out = emb*scale + norm0*scale
    k_gemm_mfma<true><<<gemm_blocks, 256, 0, stream>>>(emb, wts, bufY, nTiles, N);
    k_spmm_norm<<<spmm_blocks, 256, 0, stream>>>(row_ptr, csr, bufY, bufX,
                                                 out, emb, scale, scale, 1, N);
    // layers 1..L-1: Out += norm_l*scale
    for (int l = 1; l < L; ++l) {
        k_gemm_mfma<false><<<gemm_blocks, 256, 0, stream>>>(
            bufX, wts + (size_t)l * EMB * EMB, bufY, nTiles, N);
        k_spmm_norm<<<spmm_blocks, 256, 0, stream>>>(row_ptr, csr, bufY, bufX,
                                                     out, out, 1.0f, scale,
                                                     (l < L - 1) ? 1 : 0, N);
    }
}

// Round 7
// 977.368 us; speedup vs baseline: 1.9836x; 1.3114x over previous
//
#include <hip/hip_runtime.h>

#define EMB 100
#define EMB2 50          // bf16 pairs per row
#define XSTRIDE 52       // bf16 X row stride in dwords (16B-aligned rows)
#define Y8DW 32          // fp8 Y row stride in dwords (128 B, line-aligned)
#define BSHIFT 8         // bucket = row >> 8  (256 rows/bucket)
#define BROWS 256
#define MAXBUCK 1024
#define CHUNK 8192

typedef __attribute__((ext_vector_type(8))) short short8;
typedef __attribute__((ext_vector_type(4))) float f32x4;
typedef __attribute__((ext_vector_type(2))) float f2v;

// ---- bf16 helpers ----
__device__ __forceinline__ unsigned packbf(float a, float b) {
    unsigned ua = __float_as_uint(a), ub = __float_as_uint(b);
    unsigned ra = (ua + 0x7FFFu + ((ua >> 16) & 1u)) >> 16;   // RNE
    unsigned rb = (ub + 0x7FFFu + ((ub >> 16) & 1u)) >> 16;
    return ra | (rb << 16);
}

// ---- fp8 e4m3 (OCP) helpers ----
__device__ __forceinline__ unsigned char f32_to_fp8(float f) {
#if __has_builtin(__builtin_amdgcn_cvt_pk_fp8_f32)
    return (unsigned char)(__builtin_amdgcn_cvt_pk_fp8_f32(f, f, 0, false) & 0xFF);
#else
    unsigned u = __float_as_uint(f);
    unsigned s = (u >> 24) & 0x80u;
    unsigned mag = u & 0x7FFFFFFFu;
    if (mag >= 0x43E00000u) return (unsigned char)(s | 0x7Eu);      // clamp 448
    if (mag < 0x3C800000u) {                                        // < 2^-6: subnormal
        int r = __float2int_rn(__uint_as_float(mag) * 512.f);
        return (unsigned char)(s | (unsigned)r);
    }
    unsigned r = mag + 0x7FFFFu + ((mag >> 20) & 1u);               // RNE at bit 20
    unsigned e = r >> 23, m = (r >> 20) & 7u;
    return (unsigned char)(s | ((e - 120u) << 3) | m);
#endif
}

__device__ __forceinline__ void fma_fp8x4(unsigned g, float v,
                                          float& a0, float& a1, float& a2, float& a3) {
#if __has_builtin(__builtin_amdgcn_cvt_pk_f32_fp8)
    f2v lo = __builtin_amdgcn_cvt_pk_f32_fp8((int)g, false);
    f2v hi = __builtin_amdgcn_cvt_pk_f32_fp8((int)g, true);
    a0 = fmaf(v, lo[0], a0); a1 = fmaf(v, lo[1], a1);
    a2 = fmaf(v, hi[0], a2); a3 = fmaf(v, hi[1], a3);
#else
    float o[4];
#pragma unroll
    for (int d = 0; d < 4; ++d) {
        unsigned b = (g >> (8 * d)) & 0xFFu;
        unsigned e = (b >> 3) & 15u, m = b & 7u;
        float val = e ? __uint_as_float(((e + 120u) << 23) | (m << 20))
                      : (float)m * (1.f / 512.f);
        o[d] = (b & 0x80u) ? -val : val;
    }
    a0 = fmaf(v, o[0], a0); a1 = fmaf(v, o[1], a1);
    a2 = fmaf(v, o[2], a2); a3 = fmaf(v, o[3], a3);
#endif
}

// ---------------- bucket count (LDS-aggregated) ----------------
__global__ __launch_bounds__(256) void k_bucket_count(const int* __restrict__ rows,
                                                      int* __restrict__ gcnt,
                                                      int E, int nbuck) {
    __shared__ int hist[MAXBUCK];
    int tid = threadIdx.x;
    int base = blockIdx.x * CHUNK;
    for (int s = tid; s < nbuck; s += 256) hist[s] = 0;
    __syncthreads();
#pragma unroll
    for (int k = 0; k < CHUNK / 256; ++k) {
        int i = base + tid + k * 256;
        if (i < E) atomicAdd(&hist[rows[i] >> BSHIFT], 1);
    }
    __syncthreads();
    for (int s = tid; s < nbuck; s += 256)
        if (hist[s]) atomicAdd(&gcnt[s], hist[s]);
}

// ---------------- exclusive scan over buckets (single block) ----------------
__global__ __launch_bounds__(1024) void k_scan2(int* __restrict__ bsum, int nb) {
    __shared__ int tmp[1024];
    int v = (threadIdx.x < nb) ? bsum[threadIdx.x] : 0;
    tmp[threadIdx.x] = v;
    __syncthreads();
    for (int off = 1; off < 1024; off <<= 1) {
        int t = (threadIdx.x >= off) ? tmp[threadIdx.x - off] : 0;
        __syncthreads();
        tmp[threadIdx.x] += t;
        __syncthreads();
    }
    if (threadIdx.x < nb) bsum[threadIdx.x] = tmp[threadIdx.x] - v; // exclusive
}

// ---------------- partition into row-buckets ----------------
__global__ __launch_bounds__(256) void k_partition(const int* __restrict__ rows,
                                                   const int* __restrict__ cols,
                                                   const float* __restrict__ vals,
                                                   int* __restrict__ bucket_next,
                                                   int2* __restrict__ part,
                                                   int E, int nbuck) {
    __shared__ int hist[MAXBUCK];
    __shared__ int base_s[MAXBUCK];
    __shared__ int cnt2[MAXBUCK];
    int tid = threadIdx.x;
    int base = blockIdx.x * CHUNK;
    for (int s = tid; s < nbuck; s += 256) hist[s] = 0;
    __syncthreads();
#pragma unroll
    for (int k = 0; k < CHUNK / 256; ++k) {
        int i = base + tid + k * 256;
        if (i < E) atomicAdd(&hist[rows[i] >> BSHIFT], 1);
    }
    __syncthreads();
    for (int s = tid; s < nbuck; s += 256) {
        if (hist[s]) base_s[s] = atomicAdd(&bucket_next[s], hist[s]);
        cnt2[s] = 0;
    }
    __syncthreads();
#pragma unroll
    for (int k = 0; k < CHUNK / 256; ++k) {
        int i = base + tid + k * 256;
        if (i < E) {
            int r = rows[i];
            int b = r >> BSHIFT;
            unsigned q = (unsigned)__float2int_rn(vals[i] * 16383.f);
            unsigned cv = (unsigned)cols[i] | (q << 18);
            int rank = atomicAdd(&cnt2[b], 1);
            part[base_s[b] + rank] = make_int2(r, (int)cv);
        }
    }
}

// ---------------- per-bucket CSR finalize ----------------
__global__ __launch_bounds__(256) void k_build_csr(const int2* __restrict__ part,
                                                   const int* __restrict__ bucket_end,
                                                   int* __restrict__ row_ptr,
                                                   unsigned* __restrict__ csr,
                                                   int N, int E) {
    __shared__ int cnt[BROWS];
    __shared__ int scn[BROWS];
    __shared__ int cur[BROWS];
    int b = blockIdx.x;
    int tid = threadIdx.x;
    int seg_beg = (b == 0) ? 0 : bucket_end[b - 1];
    int seg_end = bucket_end[b];
    int rowbase = b << BSHIFT;

    cnt[tid] = 0;
    __syncthreads();
    for (int i = seg_beg + tid; i < seg_end; i += 256)
        atomicAdd(&cnt[part[i].x - rowbase], 1);
    __syncthreads();
    int v = cnt[tid];
    scn[tid] = v;
    __syncthreads();
    for (int off = 1; off < 256; off <<= 1) {
        int t = (tid >= off) ? scn[tid - off] : 0;
        __syncthreads();
        scn[tid] += t;
        __syncthreads();
    }
    int rp = seg_beg + scn[tid] - v;          // exclusive
    if (rowbase + tid < N) row_ptr[rowbase + tid] = rp;
    cur[tid] = rp;
    if (b == 0 && tid == 0) row_ptr[N] = E;
    __syncthreads();
    for (int i = seg_beg + tid; i < seg_end; i += 256) {
        int2 e = part[i];
        int pos = atomicAdd(&cur[e.x - rowbase], 1);
        csr[pos] = (unsigned)e.y;
    }
}

// ---------------- MFMA GEMM: Y8[r][e] = fp8( sum_d X[r][d] * W[e][d] ) --------
template <bool F32SRC>
__global__ __launch_bounds__(256) void k_gemm_mfma(const void* __restrict__ Xv,
                                                   const float* __restrict__ W,
                                                   unsigned char* __restrict__ Y8,
                                                   int nTiles, int N) {
    __shared__ uint4 Bf[28][64];   // [nt*4+ks][lane]
    int tid = threadIdx.x;
#pragma unroll
    for (int it = 0; it < 7; ++it) {
        int id = it * 256 + tid;
        int fs = id >> 6, lane = id & 63;
        int nt = fs >> 2, ks = fs & 3;
        int e = nt * 16 + (lane & 15);
        int dbase = ks * 32 + (lane >> 4) * 8;
        float w[8];
#pragma unroll
        for (int j = 0; j < 8; ++j) {
            int d = dbase + j;
            w[j] = (e < EMB && d < EMB) ? W[e * EMB + d] : 0.f;
        }
        uint4 u;
        u.x = packbf(w[0], w[1]); u.y = packbf(w[2], w[3]);
        u.z = packbf(w[4], w[5]); u.w = packbf(w[6], w[7]);
        Bf[fs][lane] = u;
    }
    __syncthreads();

    int wid = (blockIdx.x * 256 + tid) >> 6;
    int nWaves = gridDim.x * 4;
    int lane = tid & 63;
    int m = lane & 15, kg = lane >> 4;

    for (int tile = wid; tile < nTiles; tile += nWaves) {
        int rowbase = tile * 16;
        int arow = rowbase + m; if (arow >= N) arow = N - 1;   // clamp (masked at store)
        uint4 a[4];
        if (F32SRC) {
            const float* xr = (const float*)Xv + (size_t)arow * EMB;
#pragma unroll
            for (int ks = 0; ks < 3; ++ks) {
                float4 v0 = *(const float4*)(xr + ks * 32 + kg * 8);
                float4 v1 = *(const float4*)(xr + ks * 32 + kg * 8 + 4);
                a[ks] = make_uint4(packbf(v0.x, v0.y), packbf(v0.z, v0.w),
                                   packbf(v1.x, v1.y), packbf(v1.z, v1.w));
            }
            uint4 t = make_uint4(0, 0, 0, 0);
            if (kg == 0) { float4 v = *(const float4*)(xr + 96);
                           t.x = packbf(v.x, v.y); t.y = packbf(v.z, v.w); }
            a[3] = t;
        } else {
            const unsigned* xr = (const unsigned*)Xv + (size_t)arow * XSTRIDE;
#pragma unroll
            for (int ks = 0; ks < 3; ++ks)
                a[ks] = *(const uint4*)(xr + ks * 16 + kg * 4);
            uint4 t = make_uint4(0, 0, 0, 0);
            if (kg == 0) { uint2 v = *(const uint2*)(xr + 48); t.x = v.x; t.y = v.y; }
            a[3] = t;
        }

        f32x4 acc[7];
#pragma unroll
        for (int nt = 0; nt < 7; ++nt) acc[nt] = (f32x4){0.f, 0.f, 0.f, 0.f};
#pragma unroll
        for (int ks = 0; ks < 4; ++ks) {
            short8 av = __builtin_bit_cast(short8, a[ks]);
#pragma unroll
            for (int nt = 0; nt < 7; ++nt) {
                short8 bv = __builtin_bit_cast(short8, Bf[nt * 4 + ks][lane]);
                acc[nt] = __builtin_amdgcn_mfma_f32_16x16x32_bf16(av, bv, acc[nt], 0, 0, 0);
            }
        }
        // epilogue: fp8 byte stores, row stride 128 B
#pragma unroll
        for (int nt = 0; nt < 7; ++nt) {
            int e = nt * 16 + m;
            if (e < EMB) {
#pragma unroll
                for (int r = 0; r < 4; ++r) {
                    int rr = rowbase + kg * 4 + r;
                    if (rr < N)
                        Y8[((size_t)rr << 7) + e] = f32_to_fp8(acc[nt][r]);
                }
            }
        }
    }
}

// ---------------- SpMM + norm + mean-accumulate (fp8 gather) ----------------
// One wave per row, split into two 32-lane halves; each half processes one
// edge with 25 active lanes owning 4 fp8 dims each (1 dword gather/lane).
// Out[row] = prev[row]*pscale + normalized(acc)*scale
__global__ __launch_bounds__(256) void k_spmm_norm(const int* __restrict__ row_ptr,
                                                   const unsigned* __restrict__ csr,
                                                   const unsigned* __restrict__ Y8,
                                                   unsigned* __restrict__ Xout,
                                                   float* __restrict__ Out,
                                                   const float* __restrict__ prev,
                                                   float pscale, float scale,
                                                   int writeX, int N) {
    int wave = (blockIdx.x * 256 + threadIdx.x) >> 6;
    int lane = threadIdx.x & 63;
    if (wave >= N) return;
    int half = lane >> 5, sub = lane & 31;
    int beg = row_ptr[wave], end = row_ptr[wave + 1];
    const float dq = 1.0f / 16383.f;
    float a0 = 0.f, a1 = 0.f, a2 = 0.f, a3 = 0.f;
    if (sub < 25) {
        const unsigned* yb = Y8 + sub;
        int j = beg + half;
        for (; j + 6 < end; j += 8) {
            unsigned u0 = __builtin_nontemporal_load(&csr[j + 0]);
            unsigned u1 = __builtin_nontemporal_load(&csr[j + 2]);
            unsigned u2 = __builtin_nontemporal_load(&csr[j + 4]);
            unsigned u3 = __builtin_nontemporal_load(&csr[j + 6]);
            unsigned g0 = yb[(u0 & 0x3FFFFu) << 5];
            unsigned g1 = yb[(u1 & 0x3FFFFu) << 5];
            unsigned g2 = yb[(u2 & 0x3FFFFu) << 5];
            unsigned g3 = yb[(u3 & 0x3FFFFu) << 5];
            float v0 = (float)(u0 >> 18) * dq;
            float v1 = (float)(u1 >> 18) * dq;
            float v2 = (float)(u2 >> 18) * dq;
            float v3 = (float)(u3 >> 18) * dq;
            fma_fp8x4(g0, v0, a0, a1, a2, a3);
            fma_fp8x4(g1, v1, a0, a1, a2, a3);
            fma_fp8x4(g2, v2, a0, a1, a2, a3);
            fma_fp8x4(g3, v3, a0, a1, a2, a3);
        }
        for (; j < end; j += 2) {
            unsigned u = csr[j];
            unsigned g = yb[(u & 0x3FFFFu) << 5];
            float v = (float)(u >> 18) * dq;
            fma_fp8x4(g, v, a0, a1, a2, a3);
        }
    }
    // combine the two half-wave partial sums (lane l <-> l+32)
    a0 += __shfl_xor(a0, 32, 64);
    a1 += __shfl_xor(a1, 32, 64);
    a2 += __shfl_xor(a2, 32, 64);
    a3 += __shfl_xor(a3, 32, 64);
    float ss = fmaf(a0, a0, fmaf(a1, a1, fmaf(a2, a2, a3 * a3)));
#pragma unroll
    for (int off = 16; off; off >>= 1) ss += __shfl_xor(ss, off, 64);
    float sc = scale / fmaxf(sqrtf(ss), 1e-12f);
    if (half == 0 && sub < 25) {
        if (writeX) {
            uint2 xw;
            xw.x = packbf(a0, a1); xw.y = packbf(a2, a3);
            *(uint2*)(Xout + (size_t)wave * XSTRIDE + sub * 2) = xw;
        }
        const float4* pp = (const float4*)(prev + (size_t)wave * EMB) + sub;
        float4 p = *pp;
        float4 o;
        o.x = fmaf(a0, sc, p.x * pscale);
        o.y = fmaf(a1, sc, p.y * pscale);
        o.z = fmaf(a2, sc, p.z * pscale);
        o.w = fmaf(a3, sc, p.w * pscale);
        *((float4*)(Out + (size_t)wave * EMB) + sub) = o;
    }
}

extern "C" void kernel_launch(void* const* d_in, const int* in_sizes, int n_in,
                              void* d_out, int out_size, void* d_ws, size_t ws_size,
                              hipStream_t stream) {
    const float* emb   = (const float*)d_in[0];
    const float* avals = (const float*)d_in[1];
    const float* wts   = (const float*)d_in[2];
    const int*   arows = (const int*)d_in[3];
    const int*   acols = (const int*)d_in[4];

    const int N = in_sizes[0] / EMB;
    const int E = in_sizes[1];
    const int L = in_sizes[2] / (EMB * EMB);
    const float scale = 1.0f / (float)(L + 1);
    const int nbuck = (N + BROWS - 1) >> BSHIFT;

    // workspace layout (dwords). `part` aliases Y8/bufX (only live pre-GEMM).
    unsigned* Y8     = (unsigned*)d_ws;                      // N*Y8DW (fp8 rows)
    unsigned* bufX   = Y8 + (size_t)N * Y8DW;                // N*XSTRIDE (bf16)
    int* row_ptr     = (int*)(bufX + (size_t)N * XSTRIDE);   // N+2
    int* bucket_next = row_ptr + (N + 2);                    // MAXBUCK
    unsigned* csr    = (unsigned*)(bucket_next + MAXBUCK);   // E
    int2* part       = (int2*)d_ws;                          // E int2 (aliased)
    float* out = (float*)d_out;

    const int nchunk = (E + CHUNK - 1) / CHUNK;

    // ---- CSR build: row-bucket partition + fused per-bucket finalize ----
    hipMemsetAsync(bucket_next, 0, MAXBUCK * sizeof(int), stream);
    k_bucket_count<<<nchunk, 256, 0, stream>>>(arows, bucket_next, E, nbuck);
    k_scan2<<<1, 1024, 0, stream>>>(bucket_next, nbuck);
    k_partition<<<nchunk, 256, 0, stream>>>(arows, acols, avals, bucket_next,
                                            part, E, nbuck);
    k_build_csr<<<nbuck, 256, 0, stream>>>(part, bucket_next, row_ptr, csr, N, E);

    const int nTiles = (N + 15) / 16;
    const int gemm_blocks = 782;
    const int spmm_blocks = (N + 3) / 4;

    // layer 0: Out = emb*scale + norm0*scale
    k_gemm_mfma<true><<<gemm_blocks, 256, 0, stream>>>(emb, wts,
                                                       (unsigned char*)Y8, nTiles, N);
    k_spmm_norm<<<spmm_blocks, 256, 0, stream>>>(row_ptr, csr, Y8, bufX,
                                                 out, emb, scale, scale, 1, N);
    // layers 1..L-1: Out += norm_l*scale
    for (int l = 1; l < L; ++l) {
        k_gemm_mfma<false><<<gemm_blocks, 256, 0, stream>>>(
            bufX, wts + (size_t)l * EMB * EMB, (unsigned char*)Y8, nTiles, N);
        k_spmm_norm<<<spmm_blocks, 256, 0, stream>>>(row_ptr, csr, Y8, bufX,
                                                     out, out, 1.0f, scale,
                                                     (l < L - 1) ? 1 : 0, N);
    }
}

// Round 8
// 904.025 us; speedup vs baseline: 2.1445x; 1.0811x over previous
//
#include <hip/hip_runtime.h>

#define EMB 100
#define EMB2 50          // bf16 pairs per row
#define XSTRIDE 52       // bf16 X row stride in dwords (16B-aligned rows)
#define Y8DW 32          // fp8 Y row stride in dwords (128 B, line-aligned)
#define BSHIFT 8         // bucket = row >> 8  (256 rows/bucket)
#define BROWS 256
#define MAXBUCK 1024
#define CHUNK 32768      // edges per workgroup in bucket passes

typedef __attribute__((ext_vector_type(8))) short short8;
typedef __attribute__((ext_vector_type(4))) float f32x4;
typedef __attribute__((ext_vector_type(2))) float f2v;

// ---- bf16 helpers ----
__device__ __forceinline__ unsigned packbf(float a, float b) {
    unsigned ua = __float_as_uint(a), ub = __float_as_uint(b);
    unsigned ra = (ua + 0x7FFFu + ((ua >> 16) & 1u)) >> 16;   // RNE
    unsigned rb = (ub + 0x7FFFu + ((ub >> 16) & 1u)) >> 16;
    return ra | (rb << 16);
}

// ---- fp8 e4m3 (OCP) helpers ----
__device__ __forceinline__ unsigned char f32_to_fp8(float f) {
    unsigned u = __float_as_uint(f);
    unsigned s = (u >> 24) & 0x80u;
    unsigned mag = u & 0x7FFFFFFFu;
    if (mag >= 0x43E00000u) return (unsigned char)(s | 0x7Eu);      // clamp 448
    if (mag < 0x3C800000u) {                                        // < 2^-6: subnormal
        int r = __float2int_rn(__uint_as_float(mag) * 512.f);
        return (unsigned char)(s | (unsigned)r);
    }
    unsigned r = mag + 0x7FFFFu + ((mag >> 20) & 1u);               // RNE at bit 20
    unsigned e = r >> 23, m = (r >> 20) & 7u;
    return (unsigned char)(s | ((e - 120u) << 3) | m);
}

__device__ __forceinline__ unsigned pack4_fp8(float a0, float a1, float a2, float a3) {
#if __has_builtin(__builtin_amdgcn_cvt_pk_fp8_f32)
    int lo = __builtin_amdgcn_cvt_pk_fp8_f32(a0, a1, 0, false);
    return (unsigned)__builtin_amdgcn_cvt_pk_fp8_f32(a2, a3, lo, true);
#else
    return (unsigned)f32_to_fp8(a0) | ((unsigned)f32_to_fp8(a1) << 8) |
           ((unsigned)f32_to_fp8(a2) << 16) | ((unsigned)f32_to_fp8(a3) << 24);
#endif
}

__device__ __forceinline__ void fma_fp8x4(unsigned g, float v,
                                          float& a0, float& a1, float& a2, float& a3) {
#if __has_builtin(__builtin_amdgcn_cvt_pk_f32_fp8)
    f2v lo = __builtin_amdgcn_cvt_pk_f32_fp8((int)g, false);
    f2v hi = __builtin_amdgcn_cvt_pk_f32_fp8((int)g, true);
    a0 = fmaf(v, lo[0], a0); a1 = fmaf(v, lo[1], a1);
    a2 = fmaf(v, hi[0], a2); a3 = fmaf(v, hi[1], a3);
#else
    float o[4];
#pragma unroll
    for (int d = 0; d < 4; ++d) {
        unsigned b = (g >> (8 * d)) & 0xFFu;
        unsigned e = (b >> 3) & 15u, m = b & 7u;
        float val = e ? __uint_as_float(((e + 120u) << 23) | (m << 20))
                      : (float)m * (1.f / 512.f);
        o[d] = (b & 0x80u) ? -val : val;
    }
    a0 = fmaf(v, o[0], a0); a1 = fmaf(v, o[1], a1);
    a2 = fmaf(v, o[2], a2); a3 = fmaf(v, o[3], a3);
#endif
}

// ---------------- bucket count (LDS-aggregated) ----------------
__global__ __launch_bounds__(256) void k_bucket_count(const int* __restrict__ rows,
                                                      int* __restrict__ gcnt,
                                                      int E, int nbuck) {
    __shared__ int hist[MAXBUCK];
    int tid = threadIdx.x;
    int base = blockIdx.x * CHUNK;
    for (int s = tid; s < nbuck; s += 256) hist[s] = 0;
    __syncthreads();
#pragma unroll 4
    for (int k = 0; k < CHUNK / 256; ++k) {
        int i = base + tid + k * 256;
        if (i < E) atomicAdd(&hist[rows[i] >> BSHIFT], 1);
    }
    __syncthreads();
    for (int s = tid; s < nbuck; s += 256)
        if (hist[s]) atomicAdd(&gcnt[s], hist[s]);
}

// ---------------- exclusive scan over buckets (single block) ----------------
__global__ __launch_bounds__(1024) void k_scan2(int* __restrict__ bsum, int nb) {
    __shared__ int tmp[1024];
    int v = (threadIdx.x < nb) ? bsum[threadIdx.x] : 0;
    tmp[threadIdx.x] = v;
    __syncthreads();
    for (int off = 1; off < 1024; off <<= 1) {
        int t = (threadIdx.x >= off) ? tmp[threadIdx.x - off] : 0;
        __syncthreads();
        tmp[threadIdx.x] += t;
        __syncthreads();
    }
    if (threadIdx.x < nb) bsum[threadIdx.x] = tmp[threadIdx.x] - v; // exclusive
}

// ---------------- partition into row-buckets ----------------
__global__ __launch_bounds__(256) void k_partition(const int* __restrict__ rows,
                                                   const int* __restrict__ cols,
                                                   const float* __restrict__ vals,
                                                   int* __restrict__ bucket_next,
                                                   int2* __restrict__ part,
                                                   int E, int nbuck) {
    __shared__ int hist[MAXBUCK];
    __shared__ int base_s[MAXBUCK];
    __shared__ int cnt2[MAXBUCK];
    int tid = threadIdx.x;
    int base = blockIdx.x * CHUNK;
    for (int s = tid; s < nbuck; s += 256) hist[s] = 0;
    __syncthreads();
#pragma unroll 4
    for (int k = 0; k < CHUNK / 256; ++k) {
        int i = base + tid + k * 256;
        if (i < E) atomicAdd(&hist[rows[i] >> BSHIFT], 1);
    }
    __syncthreads();
    for (int s = tid; s < nbuck; s += 256) {
        if (hist[s]) base_s[s] = atomicAdd(&bucket_next[s], hist[s]);
        cnt2[s] = 0;
    }
    __syncthreads();
#pragma unroll 4
    for (int k = 0; k < CHUNK / 256; ++k) {
        int i = base + tid + k * 256;
        if (i < E) {
            int r = rows[i];
            int b = r >> BSHIFT;
            unsigned q = (unsigned)__float2int_rn(vals[i] * 16383.f);
            unsigned cv = (unsigned)cols[i] | (q << 18);
            int rank = atomicAdd(&cnt2[b], 1);
            part[base_s[b] + rank] = make_int2(r, (int)cv);
        }
    }
}

// ---------------- per-bucket CSR finalize ----------------
__global__ __launch_bounds__(256) void k_build_csr(const int2* __restrict__ part,
                                                   const int* __restrict__ bucket_end,
                                                   int* __restrict__ row_ptr,
                                                   unsigned* __restrict__ csr,
                                                   int N, int E) {
    __shared__ int cnt[BROWS];
    __shared__ int scn[BROWS];
    __shared__ int cur[BROWS];
    int b = blockIdx.x;
    int tid = threadIdx.x;
    int seg_beg = (b == 0) ? 0 : bucket_end[b - 1];
    int seg_end = bucket_end[b];
    int rowbase = b << BSHIFT;

    cnt[tid] = 0;
    __syncthreads();
    for (int i = seg_beg + tid; i < seg_end; i += 256)
        atomicAdd(&cnt[part[i].x - rowbase], 1);
    __syncthreads();
    int v = cnt[tid];
    scn[tid] = v;
    __syncthreads();
    for (int off = 1; off < 256; off <<= 1) {
        int t = (tid >= off) ? scn[tid - off] : 0;
        __syncthreads();
        scn[tid] += t;
        __syncthreads();
    }
    int rp = seg_beg + scn[tid] - v;          // exclusive
    if (rowbase + tid < N) row_ptr[rowbase + tid] = rp;
    cur[tid] = rp;
    if (b == 0 && tid == 0) row_ptr[N] = E;
    __syncthreads();
    for (int i = seg_beg + tid; i < seg_end; i += 256) {
        int2 e = part[i];
        int pos = atomicAdd(&cur[e.x - rowbase], 1);
        csr[pos] = (unsigned)e.y;
    }
}

// ---------------- MFMA GEMM: Y8[r][e] = fp8( sum_d X[r][d] * W[e][d] ) --------
// SWAPPED operands: mfma(Wfrag, Xfrag, acc) -> lane holds 4 consecutive e
// (= nt*16 + kg*4 + reg) for row rowbase+m -> pack 1 dword, 7 stores/tile.
template <bool F32SRC>
__global__ __launch_bounds__(256) void k_gemm_mfma(const void* __restrict__ Xv,
                                                   const float* __restrict__ W,
                                                   unsigned* __restrict__ Y8,
                                                   int nTiles, int N) {
    __shared__ uint4 Bf[28][64];   // [nt*4+ks][lane]  W fragments (bf16)
    int tid = threadIdx.x;
#pragma unroll
    for (int it = 0; it < 7; ++it) {
        int id = it * 256 + tid;
        int fs = id >> 6, lane = id & 63;
        int nt = fs >> 2, ks = fs & 3;
        int e = nt * 16 + (lane & 15);
        int dbase = ks * 32 + (lane >> 4) * 8;
        float w[8];
#pragma unroll
        for (int j = 0; j < 8; ++j) {
            int d = dbase + j;
            w[j] = (e < EMB && d < EMB) ? W[e * EMB + d] : 0.f;
        }
        uint4 u;
        u.x = packbf(w[0], w[1]); u.y = packbf(w[2], w[3]);
        u.z = packbf(w[4], w[5]); u.w = packbf(w[6], w[7]);
        Bf[fs][lane] = u;
    }
    __syncthreads();

    int wid = (blockIdx.x * 256 + tid) >> 6;
    int nWaves = gridDim.x * 4;
    int lane = tid & 63;
    int m = lane & 15, kg = lane >> 4;

    for (int tile = wid; tile < nTiles; tile += nWaves) {
        int rowbase = tile * 16;
        int arow = rowbase + m; if (arow >= N) arow = N - 1;   // clamp
        uint4 a[4];
        if (F32SRC) {
            const float* xr = (const float*)Xv + (size_t)arow * EMB;
#pragma unroll
            for (int ks = 0; ks < 3; ++ks) {
                float4 v0 = *(const float4*)(xr + ks * 32 + kg * 8);
                float4 v1 = *(const float4*)(xr + ks * 32 + kg * 8 + 4);
                a[ks] = make_uint4(packbf(v0.x, v0.y), packbf(v0.z, v0.w),
                                   packbf(v1.x, v1.y), packbf(v1.z, v1.w));
            }
            uint4 t = make_uint4(0, 0, 0, 0);
            if (kg == 0) { float4 v = *(const float4*)(xr + 96);
                           t.x = packbf(v.x, v.y); t.y = packbf(v.z, v.w); }
            a[3] = t;
        } else {
            const unsigned* xr = (const unsigned*)Xv + (size_t)arow * XSTRIDE;
#pragma unroll
            for (int ks = 0; ks < 3; ++ks)
                a[ks] = *(const uint4*)(xr + ks * 16 + kg * 4);
            uint4 t = make_uint4(0, 0, 0, 0);
            if (kg == 0) { uint2 v = *(const uint2*)(xr + 48); t.x = v.x; t.y = v.y; }
            a[3] = t;
        }

        f32x4 acc[7];
#pragma unroll
        for (int nt = 0; nt < 7; ++nt) acc[nt] = (f32x4){0.f, 0.f, 0.f, 0.f};
#pragma unroll
        for (int ks = 0; ks < 4; ++ks) {
            short8 av = __builtin_bit_cast(short8, a[ks]);
#pragma unroll
            for (int nt = 0; nt < 7; ++nt) {
                short8 bv = __builtin_bit_cast(short8, Bf[nt * 4 + ks][lane]);
                acc[nt] = __builtin_amdgcn_mfma_f32_16x16x32_bf16(bv, av, acc[nt], 0, 0, 0);
            }
        }
        // epilogue: lane owns row rowbase+m, e-block nt*16+kg*4..+3
        int rr = rowbase + m;
        if (rr < N) {
            unsigned* yrow = Y8 + ((size_t)rr << 5) + kg;
#pragma unroll
            for (int nt = 0; nt < 6; ++nt)
                yrow[nt * 4] = pack4_fp8(acc[nt][0], acc[nt][1], acc[nt][2], acc[nt][3]);
            if (kg == 0)
                yrow[24] = pack4_fp8(acc[6][0], acc[6][1], acc[6][2], acc[6][3]);
        }
    }
}

// ---------------- SpMM + norm + mean-accumulate (fp8 gather) ----------------
// One wave per row, two 32-lane halves; each half: one edge, 25 active lanes
// x 4 fp8 dims (1 dword gather/lane). 8-deep unroll per half for MLP.
__global__ __launch_bounds__(256) void k_spmm_norm(const int* __restrict__ row_ptr,
                                                   const unsigned* __restrict__ csr,
                                                   const unsigned* __restrict__ Y8,
                                                   unsigned* __restrict__ Xout,
                                                   float* __restrict__ Out,
                                                   const float* __restrict__ prev,
                                                   float pscale, float scale,
                                                   int writeX, int N) {
    int wave = (blockIdx.x * 256 + threadIdx.x) >> 6;
    int lane = threadIdx.x & 63;
    if (wave >= N) return;
    int half = lane >> 5, sub = lane & 31;
    int beg = row_ptr[wave], end = row_ptr[wave + 1];
    const float dq = 1.0f / 16383.f;
    float a0 = 0.f, a1 = 0.f, a2 = 0.f, a3 = 0.f;
    if (sub < 25) {
        const unsigned* yb = Y8 + sub;
        int j = beg + half;
        for (; j + 14 < end; j += 16) {
            unsigned u[8], g[8];
#pragma unroll
            for (int t = 0; t < 8; ++t)
                u[t] = __builtin_nontemporal_load(&csr[j + 2 * t]);
#pragma unroll
            for (int t = 0; t < 8; ++t)
                g[t] = yb[(u[t] & 0x3FFFFu) << 5];
#pragma unroll
            for (int t = 0; t < 8; ++t)
                fma_fp8x4(g[t], (float)(u[t] >> 18) * dq, a0, a1, a2, a3);
        }
        for (; j + 6 < end; j += 8) {
            unsigned u[4], g[4];
#pragma unroll
            for (int t = 0; t < 4; ++t)
                u[t] = __builtin_nontemporal_load(&csr[j + 2 * t]);
#pragma unroll
            for (int t = 0; t < 4; ++t)
                g[t] = yb[(u[t] & 0x3FFFFu) << 5];
#pragma unroll
            for (int t = 0; t < 4; ++t)
                fma_fp8x4(g[t], (float)(u[t] >> 18) * dq, a0, a1, a2, a3);
        }
        for (; j < end; j += 2) {
            unsigned u = csr[j];
            unsigned g = yb[(u & 0x3FFFFu) << 5];
            fma_fp8x4(g, (float)(u >> 18) * dq, a0, a1, a2, a3);
        }
    }
    // combine the two half-wave partial sums (lane l <-> l+32)
    a0 += __shfl_xor(a0, 32, 64);
    a1 += __shfl_xor(a1, 32, 64);
    a2 += __shfl_xor(a2, 32, 64);
    a3 += __shfl_xor(a3, 32, 64);
    float ss = fmaf(a0, a0, fmaf(a1, a1, fmaf(a2, a2, a3 * a3)));
#pragma unroll
    for (int off = 16; off; off >>= 1) ss += __shfl_xor(ss, off, 64);
    float sc = scale / fmaxf(sqrtf(ss), 1e-12f);
    if (half == 0 && sub < 25) {
        if (writeX) {
            uint2 xw;
            xw.x = packbf(a0, a1); xw.y = packbf(a2, a3);
            *(uint2*)(Xout + (size_t)wave * XSTRIDE + sub * 2) = xw;
        }
        const float4* pp = (const float4*)(prev + (size_t)wave * EMB) + sub;
        float4 p = *pp;
        float4 o;
        o.x = fmaf(a0, sc, p.x * pscale);
        o.y = fmaf(a1, sc, p.y * pscale);
        o.z = fmaf(a2, sc, p.z * pscale);
        o.w = fmaf(a3, sc, p.w * pscale);
        *((float4*)(Out + (size_t)wave * EMB) + sub) = o;
    }
}

extern "C" void kernel_launch(void* const* d_in, const int* in_sizes, int n_in,
                              void* d_out, int out_size, void* d_ws, size_t ws_size,
                              hipStream_t stream) {
    const float* emb   = (const float*)d_in[0];
    const float* avals = (const float*)d_in[1];
    const float* wts   = (const float*)d_in[2];
    const int*   arows = (const int*)d_in[3];
    const int*   acols = (const int*)d_in[4];

    const int N = in_sizes[0] / EMB;
    const int E = in_sizes[1];
    const int L = in_sizes[2] / (EMB * EMB);
    const float scale = 1.0f / (float)(L + 1);
    const int nbuck = (N + BROWS - 1) >> BSHIFT;

    // workspace layout (dwords). `part` aliases Y8/bufX (only live pre-GEMM).
    unsigned* Y8     = (unsigned*)d_ws;                      // N*Y8DW (fp8 rows)
    unsigned* bufX   = Y8 + (size_t)N * Y8DW;                // N*XSTRIDE (bf16)
    int* row_ptr     = (int*)(bufX + (size_t)N * XSTRIDE);   // N+2
    int* bucket_next = row_ptr + (N + 2);                    // MAXBUCK
    unsigned* csr    = (unsigned*)(bucket_next + MAXBUCK);   // E
    int2* part       = (int2*)d_ws;                          // E int2 (aliased)
    float* out = (float*)d_out;

    const int nchunk = (E + CHUNK - 1) / CHUNK;

    // ---- CSR build: row-bucket partition + fused per-bucket finalize ----
    hipMemsetAsync(bucket_next, 0, MAXBUCK * sizeof(int), stream);
    k_bucket_count<<<nchunk, 256, 0, stream>>>(arows, bucket_next, E, nbuck);
    k_scan2<<<1, 1024, 0, stream>>>(bucket_next, nbuck);
    k_partition<<<nchunk, 256, 0, stream>>>(arows, acols, avals, bucket_next,
                                            part, E, nbuck);
    k_build_csr<<<nbuck, 256, 0, stream>>>(part, bucket_next, row_ptr, csr, N, E);

    const int nTiles = (N + 15) / 16;
    const int gemm_blocks = 782;
    const int spmm_blocks = (N + 3) / 4;

    // layer 0: Out = emb*scale + norm0*scale
    k_gemm_mfma<true><<<gemm_blocks, 256, 0, stream>>>(emb, wts, Y8, nTiles, N);
    k_spmm_norm<<<spmm_blocks, 256, 0, stream>>>(row_ptr, csr, Y8, bufX,
                                                 out, emb, scale, scale, 1, N);
    // layers 1..L-1: Out += norm_l*scale
    for (int l = 1; l < L; ++l) {
        k_gemm_mfma<false><<<gemm_blocks, 256, 0, stream>>>(
            bufX, wts + (size_t)l * EMB * EMB, Y8, nTiles, N);
        k_spmm_norm<<<spmm_blocks, 256, 0, stream>>>(row_ptr, csr, Y8, bufX,
                                                     out, out, 1.0f, scale,
                                                     (l < L - 1) ? 1 : 0, N);
    }
}

// Round 9
// 788.163 us; speedup vs baseline: 2.4598x; 1.1470x over previous
//
#include <hip/hip_runtime.h>

#define EMB 100
#define XSTRIDE 52       // bf16 X row stride in dwords (16B-aligned rows)
#define Y8DW 32          // fp8 Y row stride in dwords (128 B, line-aligned)
#define BSHIFT 8         // bucket = row >> 8  (256 rows/bucket)
#define BROWS 256
#define MAXBUCK 1024
#define CHUNK 4096       // edges per workgroup in bucket passes
#define EPT (CHUNK / 256)

typedef __attribute__((ext_vector_type(8))) short short8;
typedef __attribute__((ext_vector_type(4))) float f32x4;
typedef __attribute__((ext_vector_type(2))) float f2v;

// ---- bf16 helpers ----
__device__ __forceinline__ unsigned packbf(float a, float b) {
    unsigned ua = __float_as_uint(a), ub = __float_as_uint(b);
    unsigned ra = (ua + 0x7FFFu + ((ua >> 16) & 1u)) >> 16;   // RNE
    unsigned rb = (ub + 0x7FFFu + ((ub >> 16) & 1u)) >> 16;
    return ra | (rb << 16);
}

// ---- fp8 e4m3 (OCP) helpers ----
__device__ __forceinline__ unsigned char f32_to_fp8(float f) {
    unsigned u = __float_as_uint(f);
    unsigned s = (u >> 24) & 0x80u;
    unsigned mag = u & 0x7FFFFFFFu;
    if (mag >= 0x43E00000u) return (unsigned char)(s | 0x7Eu);      // clamp 448
    if (mag < 0x3C800000u) {                                        // subnormal
        int r = __float2int_rn(__uint_as_float(mag) * 512.f);
        return (unsigned char)(s | (unsigned)r);
    }
    unsigned r = mag + 0x7FFFFu + ((mag >> 20) & 1u);               // RNE at bit 20
    unsigned e = r >> 23, m = (r >> 20) & 7u;
    return (unsigned char)(s | ((e - 120u) << 3) | m);
}

__device__ __forceinline__ unsigned pack4_fp8(float a0, float a1, float a2, float a3) {
#if __has_builtin(__builtin_amdgcn_cvt_pk_fp8_f32)
    int lo = __builtin_amdgcn_cvt_pk_fp8_f32(a0, a1, 0, false);
    return (unsigned)__builtin_amdgcn_cvt_pk_fp8_f32(a2, a3, lo, true);
#else
    return (unsigned)f32_to_fp8(a0) | ((unsigned)f32_to_fp8(a1) << 8) |
           ((unsigned)f32_to_fp8(a2) << 16) | ((unsigned)f32_to_fp8(a3) << 24);
#endif
}

__device__ __forceinline__ void fma_fp8x4(unsigned g, float v,
                                          float& a0, float& a1, float& a2, float& a3) {
#if __has_builtin(__builtin_amdgcn_cvt_pk_f32_fp8)
    f2v lo = __builtin_amdgcn_cvt_pk_f32_fp8((int)g, false);
    f2v hi = __builtin_amdgcn_cvt_pk_f32_fp8((int)g, true);
    a0 = fmaf(v, lo[0], a0); a1 = fmaf(v, lo[1], a1);
    a2 = fmaf(v, hi[0], a2); a3 = fmaf(v, hi[1], a3);
#else
    float o[4];
#pragma unroll
    for (int d = 0; d < 4; ++d) {
        unsigned b = (g >> (8 * d)) & 0xFFu;
        unsigned e = (b >> 3) & 15u, m = b & 7u;
        float val = e ? __uint_as_float(((e + 120u) << 23) | (m << 20))
                      : (float)m * (1.f / 512.f);
        o[d] = (b & 0x80u) ? -val : val;
    }
    a0 = fmaf(v, o[0], a0); a1 = fmaf(v, o[1], a1);
    a2 = fmaf(v, o[2], a2); a3 = fmaf(v, o[3], a3);
#endif
}

// ---------------- bucket count (LDS-aggregated) ----------------
__global__ __launch_bounds__(256) void k_bucket_count(const int* __restrict__ rows,
                                                      int* __restrict__ gcnt,
                                                      int E, int nbuck) {
    __shared__ int hist[MAXBUCK];
    int tid = threadIdx.x;
    int base = blockIdx.x * CHUNK;
    for (int s = tid; s < nbuck; s += 256) hist[s] = 0;
    __syncthreads();
#pragma unroll
    for (int k = 0; k < EPT; ++k) {
        int i = base + tid + k * 256;
        if (i < E) atomicAdd(&hist[rows[i] >> BSHIFT], 1);
    }
    __syncthreads();
    for (int s = tid; s < nbuck; s += 256)
        if (hist[s]) atomicAdd(&gcnt[s], hist[s]);
}

// ---------------- exclusive scan over buckets (single block) ----------------
__global__ __launch_bounds__(1024) void k_scan2(int* __restrict__ bsum, int nb) {
    __shared__ int tmp[1024];
    int v = (threadIdx.x < nb) ? bsum[threadIdx.x] : 0;
    tmp[threadIdx.x] = v;
    __syncthreads();
    for (int off = 1; off < 1024; off <<= 1) {
        int t = (threadIdx.x >= off) ? tmp[threadIdx.x - off] : 0;
        __syncthreads();
        tmp[threadIdx.x] += t;
        __syncthreads();
    }
    if (threadIdx.x < nb) bsum[threadIdx.x] = tmp[threadIdx.x] - v; // exclusive
}

// ---------------- partition into row-buckets (LDS-staged writes) -------------
// Stash edges in registers, LDS hist -> global reserve -> LDS scan -> place
// bucket-sorted into LDS stage -> linear sweep writes contiguous runs to part.
// Kills the 8B-random-scatter write-allocate RMW that dominated before.
__global__ __launch_bounds__(256) void k_partition(const int* __restrict__ rows,
                                                   const int* __restrict__ cols,
                                                   const float* __restrict__ vals,
                                                   int* __restrict__ bucket_next,
                                                   int2* __restrict__ part,
                                                   int E, int nbuck) {
    __shared__ int hist[MAXBUCK];      // counts, then reused as placement cursor
    __shared__ int loc[MAXBUCK];       // chunk-local exclusive offsets
    __shared__ int base_s[MAXBUCK];    // global bucket bases for this chunk
    __shared__ int scan256[256];
    __shared__ int2 stage[CHUNK];      // 32 KB bucket-sorted staging
    int tid = threadIdx.x;
    int base = blockIdx.x * CHUNK;
    int nE = E - base; if (nE > CHUNK) nE = CHUNK;

    for (int s = tid; s < nbuck; s += 256) hist[s] = 0;
    __syncthreads();

    int r_[EPT]; unsigned cv_[EPT];
#pragma unroll
    for (int k = 0; k < EPT; ++k) {
        int o = tid + k * 256;
        if (o < nE) {
            int i = base + o;
            int r = rows[i];
            unsigned q = (unsigned)__float2int_rn(vals[i] * 16383.f);
            r_[k] = r;
            cv_[k] = (unsigned)cols[i] | (q << 18);
            atomicAdd(&hist[r >> BSHIFT], 1);
        } else { r_[k] = -1; cv_[k] = 0; }
    }
    __syncthreads();

    // reserve global space per bucket
    for (int s = tid; s < nbuck; s += 256)
        base_s[s] = hist[s] ? atomicAdd(&bucket_next[s], hist[s]) : 0;

    // two-level exclusive scan of hist -> loc (each thread owns 4 buckets)
    int s4 = tid * 4;
    int h0 = (s4     < nbuck) ? hist[s4]     : 0;
    int h1 = (s4 + 1 < nbuck) ? hist[s4 + 1] : 0;
    int h2 = (s4 + 2 < nbuck) ? hist[s4 + 2] : 0;
    int h3 = (s4 + 3 < nbuck) ? hist[s4 + 3] : 0;
    int tot = h0 + h1 + h2 + h3;
    scan256[tid] = tot;
    __syncthreads();
    for (int off = 1; off < 256; off <<= 1) {
        int t = (tid >= off) ? scan256[tid - off] : 0;
        __syncthreads();
        scan256[tid] += t;
        __syncthreads();
    }
    int excl = scan256[tid] - tot;
    if (s4     < nbuck) { loc[s4]     = excl;                hist[s4]     = 0; }
    if (s4 + 1 < nbuck) { loc[s4 + 1] = excl + h0;           hist[s4 + 1] = 0; }
    if (s4 + 2 < nbuck) { loc[s4 + 2] = excl + h0 + h1;      hist[s4 + 2] = 0; }
    if (s4 + 3 < nbuck) { loc[s4 + 3] = excl + h0 + h1 + h2; hist[s4 + 3] = 0; }
    __syncthreads();

    // place bucket-sorted into LDS stage (hist now = cursors)
#pragma unroll
    for (int k = 0; k < EPT; ++k) {
        if (r_[k] >= 0) {
            int b = r_[k] >> BSHIFT;
            int rank = atomicAdd(&hist[b], 1);
            stage[loc[b] + rank] = make_int2(r_[k], (int)cv_[k]);
        }
    }
    __syncthreads();

    // linear sweep -> coalesced contiguous per-bucket runs in part
    for (int k = tid; k < nE; k += 256) {
        int2 e = stage[k];
        int b = e.x >> BSHIFT;
        part[base_s[b] + (k - loc[b])] = e;
    }
}

// ---------------- per-bucket CSR finalize ----------------
__global__ __launch_bounds__(256) void k_build_csr(const int2* __restrict__ part,
                                                   const int* __restrict__ bucket_end,
                                                   int* __restrict__ row_ptr,
                                                   unsigned* __restrict__ csr,
                                                   int N, int E) {
    __shared__ int cnt[BROWS];
    __shared__ int scn[BROWS];
    __shared__ int cur[BROWS];
    int b = blockIdx.x;
    int tid = threadIdx.x;
    int seg_beg = (b == 0) ? 0 : bucket_end[b - 1];
    int seg_end = bucket_end[b];
    int rowbase = b << BSHIFT;

    cnt[tid] = 0;
    __syncthreads();
    for (int i = seg_beg + tid; i < seg_end; i += 256)
        atomicAdd(&cnt[part[i].x - rowbase], 1);
    __syncthreads();
    int v = cnt[tid];
    scn[tid] = v;
    __syncthreads();
    for (int off = 1; off < 256; off <<= 1) {
        int t = (tid >= off) ? scn[tid - off] : 0;
        __syncthreads();
        scn[tid] += t;
        __syncthreads();
    }
    int rp = seg_beg + scn[tid] - v;          // exclusive
    if (rowbase + tid < N) row_ptr[rowbase + tid] = rp;
    cur[tid] = rp;
    if (b == 0 && tid == 0) row_ptr[N] = E;
    __syncthreads();
    for (int i = seg_beg + tid; i < seg_end; i += 256) {
        int2 e = part[i];
        int pos = atomicAdd(&cur[e.x - rowbase], 1);
        csr[pos] = (unsigned)e.y;
    }
}

// ---------------- MFMA GEMM: Y8[r][e] = fp8( sum_d X[r][d] * W[e][d] ) --------
// Swapped operands: lane holds rows' 4 consecutive e -> 1 packed dword store.
// Also zeroes pad dword 25 (bytes 100-103) so spmm's 8B gathers are clean.
template <bool F32SRC>
__global__ __launch_bounds__(256) void k_gemm_mfma(const void* __restrict__ Xv,
                                                   const float* __restrict__ W,
                                                   unsigned* __restrict__ Y8,
                                                   int nTiles, int N) {
    __shared__ uint4 Bf[28][64];   // [nt*4+ks][lane]  W fragments (bf16)
    int tid = threadIdx.x;
#pragma unroll
    for (int it = 0; it < 7; ++it) {
        int id = it * 256 + tid;
        int fs = id >> 6, lane = id & 63;
        int nt = fs >> 2, ks = fs & 3;
        int e = nt * 16 + (lane & 15);
        int dbase = ks * 32 + (lane >> 4) * 8;
        float w[8];
#pragma unroll
        for (int j = 0; j < 8; ++j) {
            int d = dbase + j;
            w[j] = (e < EMB && d < EMB) ? W[e * EMB + d] : 0.f;
        }
        uint4 u;
        u.x = packbf(w[0], w[1]); u.y = packbf(w[2], w[3]);
        u.z = packbf(w[4], w[5]); u.w = packbf(w[6], w[7]);
        Bf[fs][lane] = u;
    }
    __syncthreads();

    int wid = (blockIdx.x * 256 + tid) >> 6;
    int nWaves = gridDim.x * 4;
    int lane = tid & 63;
    int m = lane & 15, kg = lane >> 4;

    for (int tile = wid; tile < nTiles; tile += nWaves) {
        int rowbase = tile * 16;
        int arow = rowbase + m; if (arow >= N) arow = N - 1;   // clamp
        uint4 a[4];
        if (F32SRC) {
            const float* xr = (const float*)Xv + (size_t)arow * EMB;
#pragma unroll
            for (int ks = 0; ks < 3; ++ks) {
                float4 v0 = *(const float4*)(xr + ks * 32 + kg * 8);
                float4 v1 = *(const float4*)(xr + ks * 32 + kg * 8 + 4);
                a[ks] = make_uint4(packbf(v0.x, v0.y), packbf(v0.z, v0.w),
                                   packbf(v1.x, v1.y), packbf(v1.z, v1.w));
            }
            uint4 t = make_uint4(0, 0, 0, 0);
            if (kg == 0) { float4 v = *(const float4*)(xr + 96);
                           t.x = packbf(v.x, v.y); t.y = packbf(v.z, v.w); }
            a[3] = t;
        } else {
            const unsigned* xr = (const unsigned*)Xv + (size_t)arow * XSTRIDE;
#pragma unroll
            for (int ks = 0; ks < 3; ++ks)
                a[ks] = *(const uint4*)(xr + ks * 16 + kg * 4);
            uint4 t = make_uint4(0, 0, 0, 0);
            if (kg == 0) { uint2 v = *(const uint2*)(xr + 48); t.x = v.x; t.y = v.y; }
            a[3] = t;
        }

        f32x4 acc[7];
#pragma unroll
        for (int nt = 0; nt < 7; ++nt) acc[nt] = (f32x4){0.f, 0.f, 0.f, 0.f};
#pragma unroll
        for (int ks = 0; ks < 4; ++ks) {
            short8 av = __builtin_bit_cast(short8, a[ks]);
#pragma unroll
            for (int nt = 0; nt < 7; ++nt) {
                short8 bv = __builtin_bit_cast(short8, Bf[nt * 4 + ks][lane]);
                acc[nt] = __builtin_amdgcn_mfma_f32_16x16x32_bf16(bv, av, acc[nt], 0, 0, 0);
            }
        }
        // epilogue: lane owns row rowbase+m, e-block nt*16+kg*4..+3
        int rr = rowbase + m;
        if (rr < N) {
            unsigned* yrow = Y8 + ((size_t)rr << 5) + kg;
#pragma unroll
            for (int nt = 0; nt < 6; ++nt)
                yrow[nt * 4] = pack4_fp8(acc[nt][0], acc[nt][1], acc[nt][2], acc[nt][3]);
            if (kg == 0)
                yrow[24] = pack4_fp8(acc[6][0], acc[6][1], acc[6][2], acc[6][3]);
            if (kg == 1)
                yrow[24] = 0;   // zero pad bytes 100-103 (dword 25)
        }
    }
}

// ---------------- SpMM + norm + mean-accumulate (fp8 dwordx2 gather) ---------
// One wave per row; 4 groups x 16 lanes. Group g handles edges j==g mod 4;
// lane lg of a group gathers 8 B (dims 8lg..8lg+7). Lanes lg>=13 gather row
// padding and are excluded from the reduction.
__global__ __launch_bounds__(256) void k_spmm_norm(const int* __restrict__ row_ptr,
                                                   const unsigned* __restrict__ csr,
                                                   const unsigned* __restrict__ Y8,
                                                   unsigned* __restrict__ Xout,
                                                   float* __restrict__ Out,
                                                   const float* __restrict__ prev,
                                                   float pscale, float scale,
                                                   int writeX, int N) {
    int wave = (blockIdx.x * 256 + threadIdx.x) >> 6;
    int lane = threadIdx.x & 63;
    if (wave >= N) return;
    int g = lane >> 4, lg = lane & 15;
    int beg = row_ptr[wave], end = row_ptr[wave + 1];
    const float dq = 1.0f / 16383.f;
    float a0 = 0.f, a1 = 0.f, a2 = 0.f, a3 = 0.f;
    float a4 = 0.f, a5 = 0.f, a6 = 0.f, a7 = 0.f;
    const unsigned char* Yb = (const unsigned char*)Y8;

    if (beg < end) {
        for (int j4 = beg; j4 < end; j4 += 32) {
#pragma unroll
            for (int t = 0; t < 8; ++t) {
                int je = j4 + t * 4 + g;
                bool ok = je < end;
                unsigned u = __builtin_nontemporal_load(&csr[ok ? je : beg]);
                float v = ok ? (float)(u >> 18) * dq : 0.f;
                uint2 gg = *(const uint2*)(Yb + ((size_t)(u & 0x3FFFFu) << 7) + lg * 8);
                fma_fp8x4(gg.x, v, a0, a1, a2, a3);
                fma_fp8x4(gg.y, v, a4, a5, a6, a7);
            }
        }
    }
    // combine the 4 groups (same lg across groups holds same dims)
    a0 += __shfl_xor(a0, 16, 64); a0 += __shfl_xor(a0, 32, 64);
    a1 += __shfl_xor(a1, 16, 64); a1 += __shfl_xor(a1, 32, 64);
    a2 += __shfl_xor(a2, 16, 64); a2 += __shfl_xor(a2, 32, 64);
    a3 += __shfl_xor(a3, 16, 64); a3 += __shfl_xor(a3, 32, 64);
    a4 += __shfl_xor(a4, 16, 64); a4 += __shfl_xor(a4, 32, 64);
    a5 += __shfl_xor(a5, 16, 64); a5 += __shfl_xor(a5, 32, 64);
    a6 += __shfl_xor(a6, 16, 64); a6 += __shfl_xor(a6, 32, 64);
    a7 += __shfl_xor(a7, 16, 64); a7 += __shfl_xor(a7, 32, 64);

    float ss = 0.f;
    if (lg < 13) {
        ss = a0 * a0 + a1 * a1 + a2 * a2 + a3 * a3 +
             a4 * a4 + a5 * a5 + a6 * a6 + a7 * a7;   // lane12 a4..a7 == 0 (pad zeroed)
    }
#pragma unroll
    for (int off = 1; off < 16; off <<= 1) ss += __shfl_xor(ss, off, 64);
    float sc = scale / fmaxf(sqrtf(ss), 1e-12f);

    if (lane < 13) {   // group 0 writes; lane == lg
        if (writeX) {
            unsigned* xp = Xout + (size_t)wave * XSTRIDE + lane * 4;
            if (lane < 12) {
                uint4 xw;
                xw.x = packbf(a0, a1); xw.y = packbf(a2, a3);
                xw.z = packbf(a4, a5); xw.w = packbf(a6, a7);
                *(uint4*)xp = xw;
            } else {
                uint2 xw; xw.x = packbf(a0, a1); xw.y = packbf(a2, a3);
                *(uint2*)xp = xw;
            }
        }
        const float* pr = prev + (size_t)wave * EMB + lane * 8;
        float* op = Out + (size_t)wave * EMB + lane * 8;
        float4 p0 = *(const float4*)pr;
        float4 o0;
        o0.x = fmaf(a0, sc, p0.x * pscale);
        o0.y = fmaf(a1, sc, p0.y * pscale);
        o0.z = fmaf(a2, sc, p0.z * pscale);
        o0.w = fmaf(a3, sc, p0.w * pscale);
        *(float4*)op = o0;
        if (lane < 12) {
            float4 p1 = *(const float4*)(pr + 4);
            float4 o1;
            o1.x = fmaf(a4, sc, p1.x * pscale);
            o1.y = fmaf(a5, sc, p1.y * pscale);
            o1.z = fmaf(a6, sc, p1.z * pscale);
            o1.w = fmaf(a7, sc, p1.w * pscale);
            *(float4*)(op + 4) = o1;
        }
    }
}

extern "C" void kernel_launch(void* const* d_in, const int* in_sizes, int n_in,
                              void* d_out, int out_size, void* d_ws, size_t ws_size,
                              hipStream_t stream) {
    const float* emb   = (const float*)d_in[0];
    const float* avals = (const float*)d_in[1];
    const float* wts   = (const float*)d_in[2];
    const int*   arows = (const int*)d_in[3];
    const int*   acols = (const int*)d_in[4];

    const int N = in_sizes[0] / EMB;
    const int E = in_sizes[1];
    const int L = in_sizes[2] / (EMB * EMB);
    const float scale = 1.0f / (float)(L + 1);
    const int nbuck = (N + BROWS - 1) >> BSHIFT;

    // workspace layout (dwords). `part` aliases Y8/bufX (only live pre-GEMM).
    unsigned* Y8     = (unsigned*)d_ws;                      // N*Y8DW (fp8 rows)
    unsigned* bufX   = Y8 + (size_t)N * Y8DW;                // N*XSTRIDE (bf16)
    int* row_ptr     = (int*)(bufX + (size_t)N * XSTRIDE);   // N+2
    int* bucket_next = row_ptr + (N + 2);                    // MAXBUCK
    unsigned* csr    = (unsigned*)(bucket_next + MAXBUCK);   // E
    int2* part       = (int2*)d_ws;                          // E int2 (aliased)
    float* out = (float*)d_out;

    const int nchunk = (E + CHUNK - 1) / CHUNK;

    // ---- CSR build ----
    hipMemsetAsync(bucket_next, 0, MAXBUCK * sizeof(int), stream);
    k_bucket_count<<<nchunk, 256, 0, stream>>>(arows, bucket_next, E, nbuck);
    k_scan2<<<1, 1024, 0, stream>>>(bucket_next, nbuck);
    k_partition<<<nchunk, 256, 0, stream>>>(arows, acols, avals, bucket_next,
                                            part, E, nbuck);
    k_build_csr<<<nbuck, 256, 0, stream>>>(part, bucket_next, row_ptr, csr, N, E);

    const int nTiles = (N + 15) / 16;
    const int gemm_blocks = 782;
    const int spmm_blocks = (N + 3) / 4;

    // layer 0: Out = emb*scale + norm0*scale
    k_gemm_mfma<true><<<gemm_blocks, 256, 0, stream>>>(emb, wts, Y8, nTiles, N);
    k_spmm_norm<<<spmm_blocks, 256, 0, stream>>>(row_ptr, csr, Y8, bufX,
                                                 out, emb, scale, scale, 1, N);
    // layers 1..L-1: Out += norm_l*scale
    for (int l = 1; l < L; ++l) {
        k_gemm_mfma<false><<<gemm_blocks, 256, 0, stream>>>(
            bufX, wts + (size_t)l * EMB * EMB, Y8, nTiles, N);
        k_spmm_norm<<<spmm_blocks, 256, 0, stream>>>(row_ptr, csr, Y8, bufX,
                                                     out, out, 1.0f, scale,
                                                     (l < L - 1) ? 1 : 0, N);
    }
}